// Round 7
// baseline (227.711 us; speedup 1.0000x reference)
//
#include <hip/hip_runtime.h>

typedef __bf16 bf16x8 __attribute__((ext_vector_type(8)));
typedef float  f32x4  __attribute__((ext_vector_type(4)));

#define NPIX   65536
#define CCH    64
#define KCODE  1024
#define HW     4096
#define Q_ELEMS 4194304
#define LOSS0_OFF 4194304
#define LOSS1_OFF 4194305
#define IDX_OFF   4194306
#define WINDOW 1.0e-4f

// ws layout (bytes)
#define WS_EBP  0        // 262144: E as bf16 hi/lo MFMA-B fragments [tile][s][h][lane]*16B
#define WS_SE1  262144   // 4096: 1.0f + np.sum(e*e)  (shifted norm, scores > 0)
#define WS_SEX  266240   // 4096: np.sum(e*e) exact np order (fix path)

// numpy pairwise_sum middle branch for n=64 on squares (bit-exact np.sum(x*x))
template <typename F>
__device__ __forceinline__ float np_pairwise64_sq(F v) {
    float r[8];
#pragma unroll
    for (int j = 0; j < 8; ++j) r[j] = __fmul_rn(v(j), v(j));
#pragma unroll
    for (int i = 8; i < 64; i += 8) {
#pragma unroll
        for (int j = 0; j < 8; ++j)
            r[j] = __fadd_rn(r[j], __fmul_rn(v(i + j), v(i + j)));
    }
    return __fadd_rn(
        __fadd_rn(__fadd_rn(r[0], r[1]), __fadd_rn(r[2], r[3])),
        __fadd_rn(__fadd_rn(r[4], r[5]), __fadd_rn(r[6], r[7])));
}

// ---- prep: pack E into bf16 hi/lo B-fragments, norms, zero loss slots ----
__global__ void prep_kernel(const float* __restrict__ emb, char* __restrict__ ws,
                            float* __restrict__ out) {
    const int tid = blockIdx.x * 256 + threadIdx.x;     // 0..17407
    if (tid < 16384) {
        const int lane = tid & 63, rest = tid >> 6;
        const int h = rest & 1, s = (rest >> 1) & 1, t = rest >> 2;  // tile 0..63
        const int n = lane & 15, q = lane >> 4;
        const float* src = emb + (size_t)(t * 16 + n) * CCH + s * 32 + q * 8;
        bf16x8 f;
#pragma unroll
        for (int j = 0; j < 8; ++j) {
            float v = src[j];
            __bf16 hi = (__bf16)v;
            f[j] = (h == 0) ? hi : (__bf16)__fsub_rn(v, (float)hi);
        }
        *(bf16x8*)(ws + WS_EBP + (size_t)tid * 16) = f;
    } else if (tid < 16384 + KCODE) {
        const int k = tid - 16384;
        const float* e = emb + (size_t)k * CCH;
        float se = np_pairwise64_sq([&](int i) { return e[i]; });
        ((float*)(ws + WS_SEX))[k] = se;
        ((float*)(ws + WS_SE1))[k] = __fadd_rn(1.0f, se);
    }
    if (tid == 0) { out[LOSS0_OFF] = 0.f; out[LOSS1_OFF] = 0.f; }
}

// ---- fused: MFMA approx scores + top-2 flag + in-block exact fix + epilogue ----
// Block = 256 thr = 4 waves, owns 64 pixels start-to-finish. No K-loop barriers:
// B-fragments read straight from global (L2-resident 256 KB).
__launch_bounds__(256, 4)
__global__ void vq_all(const float* __restrict__ z, const float* __restrict__ emb,
                       const char* __restrict__ ws, float* __restrict__ out) {
    __shared__ float ztf[256 * 17];      // [(w*64+c)*17 + p] , stride 17: conflict-free
    __shared__ float szz_sh[64];
    __shared__ int   s_kfinal[64];
    __shared__ int   s_flag[64];
    __shared__ int   s_cnt;
    __shared__ float s_red[4];

    const int t = threadIdx.x, lane = t & 63, w = t >> 6;
    const int n = lane & 15, q = lane >> 4;
    const int pix0 = blockIdx.x * 64;
    const int b = pix0 >> 12, hw0 = pix0 & 4095;
    const int hwb = hw0 + w * 16;

    const float* se1 = (const float*)(ws + WS_SE1);
    const float* sex = (const float*)(ws + WS_SEX);

    if (t == 0) s_cnt = 0;

    // stage z: lane = channel, 16 pixels; transpose into LDS (stride-17 rows)
    {
        const float4* zrow = (const float4*)(z + (size_t)(b * CCH + lane) * HW + hwb);
        float4 a0 = zrow[0], a1 = zrow[1], a2 = zrow[2], a3 = zrow[3];
        float* zr = ztf + (w * 64 + lane) * 17;
        zr[0] = a0.x; zr[1] = a0.y; zr[2] = a0.z; zr[3] = a0.w;
        zr[4] = a1.x; zr[5] = a1.y; zr[6] = a1.z; zr[7] = a1.w;
        zr[8] = a2.x; zr[9] = a2.y; zr[10] = a2.z; zr[11] = a2.w;
        zr[12] = a3.x; zr[13] = a3.y; zr[14] = a3.z; zr[15] = a3.w;
    }
    __syncthreads();

    if (t < 64)   // exact np-order ||z||^2 per pixel (used by fix path)
        szz_sh[t] = np_pairwise64_sq(
            [&](int i) { return ztf[((t >> 4) * 64 + i) * 17 + (t & 15)]; });

    // A fragments (hi/lo), wave-local rows of ztf
    bf16x8 Ah0, Ah1, Al0, Al1;
#pragma unroll
    for (int j = 0; j < 8; ++j) {
        float v0 = ztf[(w * 64 + q * 8 + j) * 17 + n];
        float v1 = ztf[(w * 64 + 32 + q * 8 + j) * 17 + n];
        __bf16 h0 = (__bf16)v0, h1 = (__bf16)v1;
        Ah0[j] = h0; Al0[j] = (__bf16)__fsub_rn(v0, (float)h0);
        Ah1[j] = h1; Al1[j] = (__bf16)__fsub_rn(v1, (float)h1);
    }

    float b0d[4], b1d[4]; int b0k[4];
#pragma unroll
    for (int e = 0; e < 4; ++e) { b0d[e] = 3.0e38f; b1d[e] = 3.0e38f; b0k[e] = 0; }

    // K-loop: 64 tiles x 16 codes, zero barriers, B direct from global (L2)
    const char* ebp = ws + WS_EBP + (size_t)lane * 16;
#pragma unroll 4
    for (int tile = 0; tile < 64; ++tile) {
        const char* base = ebp + (size_t)tile * 4096;
        bf16x8 Bh0 = *(const bf16x8*)(base);
        bf16x8 Bl0 = *(const bf16x8*)(base + 1024);
        bf16x8 Bh1 = *(const bf16x8*)(base + 2048);
        bf16x8 Bl1 = *(const bf16x8*)(base + 3072);
        const int kk = tile * 16 + n;
        const float se1v = se1[kk];
        f32x4 acc = {0.f, 0.f, 0.f, 0.f};
        acc = __builtin_amdgcn_mfma_f32_16x16x32_bf16(Ah0, Bh0, acc, 0, 0, 0);
        acc = __builtin_amdgcn_mfma_f32_16x16x32_bf16(Ah1, Bh1, acc, 0, 0, 0);
        acc = __builtin_amdgcn_mfma_f32_16x16x32_bf16(Ah0, Bl0, acc, 0, 0, 0);
        acc = __builtin_amdgcn_mfma_f32_16x16x32_bf16(Ah1, Bl1, acc, 0, 0, 0);
        acc = __builtin_amdgcn_mfma_f32_16x16x32_bf16(Al0, Bh0, acc, 0, 0, 0);
        acc = __builtin_amdgcn_mfma_f32_16x16x32_bf16(Al1, Bh1, acc, 0, 0, 0);
#pragma unroll
        for (int e = 0; e < 4; ++e) {
            float d = __builtin_fmaf(-2.0f, acc[e], se1v);      // 1+se-2dot > 0
            bool take = d < b0d[e];
            b1d[e] = fminf(fmaxf(d, b0d[e]), b1d[e]);           // new 2nd-best
            b0k[e] = take ? kk : b0k[e];
            b0d[e] = fminf(b0d[e], d);
        }
    }

    // merge top-2 across the 16 col-lanes of each quad group
#pragma unroll
    for (int m = 1; m < 16; m <<= 1) {
#pragma unroll
        for (int e = 0; e < 4; ++e) {
            float od = __shfl_xor(b0d[e], m, 16);
            int   ok = __shfl_xor(b0k[e], m, 16);
            float o1 = __shfl_xor(b1d[e], m, 16);
            b1d[e] = fminf(fminf(b1d[e], o1), fmaxf(b0d[e], od));
            bool take = (od < b0d[e]) || (od == b0d[e] && ok < b0k[e]);
            b0d[e] = take ? od : b0d[e];
            b0k[e] = take ? ok : b0k[e];
        }
    }
#pragma unroll
    for (int e = 0; e < 4; ++e) {
        if (n == e) {                                   // one writer per row q*4+e
            int local = w * 16 + q * 4 + e;
            s_kfinal[local] = b0k[e];
            if (__fsub_rn(b1d[e], b0d[e]) <= WINDOW) {
                int pos = atomicAdd(&s_cnt, 1);
                s_flag[pos] = local;
            }
        }
    }
    __syncthreads();

    // in-block exact fix (bit-exact reference numerics), one wave per flagged pixel
    const int cnt = s_cnt;
    for (int i = w; i < cnt; i += 4) {
        const int l = s_flag[i];
        float zv[64];
#pragma unroll
        for (int c = 0; c < 64; ++c)
            zv[c] = ztf[((l >> 4) * 64 + c) * 17 + (l & 15)];   // broadcast reads
        const float szz = szz_sh[l];
        unsigned long long best = ~0ULL;
        for (int it = 0; it < 16; ++it) {
            const int k = it * 64 + lane;
            const float* ek = emb + (size_t)k * CCH;
            float dot = 0.f;
#pragma unroll
            for (int c = 0; c < 64; ++c) dot = __builtin_fmaf(zv[c], ek[c], dot);
            float d = __fsub_rn(__fadd_rn(szz, sex[k]), __fadd_rn(dot, dot));
            unsigned long long cand =
                ((unsigned long long)__float_as_uint(d) << 32) | (unsigned)k;
            best = cand < best ? cand : best;
        }
#pragma unroll
        for (int m = 1; m < 64; m <<= 1) {
            unsigned long long o = __shfl_xor(best, m, 64);
            best = o < best ? o : best;
        }
        if (lane == 0) s_kfinal[l] = (int)(unsigned)best;
    }
    __syncthreads();

    // epilogue: gather + STE q-write + idx + losses (z from LDS, no re-read)
    float lsum = 0.f;
    {
        const int p = t & 63, cs = t >> 6;
        const int k = s_kfinal[p];
#pragma unroll
        for (int j = 0; j < 16; ++j) {
            const int c = cs * 16 + j;
            float e    = emb[(size_t)k * CCH + c];
            float zc   = ztf[((p >> 4) * 64 + c) * 17 + (p & 15)];
            float diff = __fsub_rn(e, zc);
            out[(size_t)(b * CCH + c) * HW + hw0 + p] = __fadd_rn(zc, diff);
            lsum = __builtin_fmaf(diff, diff, lsum);
        }
    }
    if (t < 64) out[IDX_OFF + pix0 + t] = (float)s_kfinal[t];
#pragma unroll
    for (int off = 32; off > 0; off >>= 1) lsum += __shfl_down(lsum, off, 64);
    if (lane == 0) s_red[w] = lsum;
    __syncthreads();
    if (t == 0) {
        float v = (s_red[0] + s_red[1] + s_red[2] + s_red[3]) * (1.0f / (float)Q_ELEMS);
        atomicAdd(out + LOSS0_OFF, v);
        atomicAdd(out + LOSS1_OFF, v);
    }
}

extern "C" void kernel_launch(void* const* d_in, const int* in_sizes, int n_in,
                              void* d_out, int out_size, void* d_ws, size_t ws_size,
                              hipStream_t stream) {
    const float* z   = (const float*)d_in[0];
    const float* emb = (const float*)d_in[1];
    float* out = (float*)d_out;
    char* ws = (char*)d_ws;

    prep_kernel<<<dim3(68),   dim3(256), 0, stream>>>(emb, ws, out);
    vq_all     <<<dim3(1024), dim3(256), 0, stream>>>(z, emb, ws, out);
}

// Round 8
// 219.986 us; speedup vs baseline: 1.0351x; 1.0351x over previous
//
#include <hip/hip_runtime.h>

typedef __bf16 bf16x8 __attribute__((ext_vector_type(8)));
typedef float  f32x4  __attribute__((ext_vector_type(4)));

#define NPIX   65536
#define CCH    64
#define KCODE  1024
#define HW     4096
#define Q_ELEMS 4194304
#define LOSS0_OFF 4194304
#define LOSS1_OFF 4194305
#define IDX_OFF   4194306
#define WINDOW 1.0e-4f

// ws layout (bytes)
#define WS_EBP  0        // 262144: E as bf16 hi/lo MFMA-B fragments [tile][s][h][lane]*16B
#define WS_SE1  262144   // 4096: 1.0f + np.sum(e*e)  (shifted norm, scores > 0)
#define WS_SEX  266240   // 4096: np.sum(e*e) exact np order (fix path)

// numpy pairwise_sum middle branch for n=64 on squares (bit-exact np.sum(x*x))
template <typename F>
__device__ __forceinline__ float np_pairwise64_sq(F v) {
    float r[8];
#pragma unroll
    for (int j = 0; j < 8; ++j) r[j] = __fmul_rn(v(j), v(j));
#pragma unroll
    for (int i = 8; i < 64; i += 8) {
#pragma unroll
        for (int j = 0; j < 8; ++j)
            r[j] = __fadd_rn(r[j], __fmul_rn(v(i + j), v(i + j)));
    }
    return __fadd_rn(
        __fadd_rn(__fadd_rn(r[0], r[1]), __fadd_rn(r[2], r[3])),
        __fadd_rn(__fadd_rn(r[4], r[5]), __fadd_rn(r[6], r[7])));
}

// ---- prep: pack E into bf16 hi/lo B-fragments, norms, zero loss slots ----
__global__ void prep_kernel(const float* __restrict__ emb, char* __restrict__ ws,
                            float* __restrict__ out) {
    const int tid = blockIdx.x * 256 + threadIdx.x;     // 0..17407
    if (tid < 16384) {
        const int lane = tid & 63, rest = tid >> 6;
        const int h = rest & 1, s = (rest >> 1) & 1, t = rest >> 2;  // tile 0..63
        const int n = lane & 15, q = lane >> 4;
        const float* src = emb + (size_t)(t * 16 + n) * CCH + s * 32 + q * 8;
        bf16x8 f;
#pragma unroll
        for (int j = 0; j < 8; ++j) {
            float v = src[j];
            __bf16 hi = (__bf16)v;
            f[j] = (h == 0) ? hi : (__bf16)__fsub_rn(v, (float)hi);
        }
        *(bf16x8*)(ws + WS_EBP + (size_t)tid * 16) = f;
    } else if (tid < 16384 + KCODE) {
        const int k = tid - 16384;
        const float* e = emb + (size_t)k * CCH;
        float se = np_pairwise64_sq([&](int i) { return e[i]; });
        ((float*)(ws + WS_SEX))[k] = se;
        ((float*)(ws + WS_SE1))[k] = __fadd_rn(1.0f, se);
    }
    if (tid == 0) { out[LOSS0_OFF] = 0.f; out[LOSS1_OFF] = 0.f; }
}

// ---- fused: MFMA approx + top-2 flag + in-block exact fix + epilogue ----
// Block = 256 thr = 4 waves, 64 pixels. B staged per 64-code chunk in LDS
// (block-shared; kills the R7 L2 hotspot), single buffer, 2 barriers/chunk.
__launch_bounds__(256, 2)
__global__ void vq_all(const float* __restrict__ z, const float* __restrict__ emb,
                       const char* __restrict__ ws, float* __restrict__ out) {
    __shared__ float ztf[256 * 17];      // [(w*64+c)*17 + p], stride 17: conflict-free
    __shared__ __align__(16) char ldsB[16384];   // one 64-code chunk of B-frags
    __shared__ float szz_sh[64];
    __shared__ int   s_kfinal[64];
    __shared__ int   s_flag[64];
    __shared__ int   s_cnt;
    __shared__ float s_red[4];

    const int t = threadIdx.x, lane = t & 63, w = t >> 6;
    const int n = lane & 15, q = lane >> 4;
    const int pix0 = blockIdx.x * 64;
    const int b = pix0 >> 12, hw0 = pix0 & 4095;
    const int hwb = hw0 + w * 16;

    const float* se1 = (const float*)(ws + WS_SE1);
    const float* sex = (const float*)(ws + WS_SEX);

    if (t == 0) s_cnt = 0;

    // stage z: lane = channel, 16 pixels; transpose into LDS (stride-17 rows)
    {
        const float4* zrow = (const float4*)(z + (size_t)(b * CCH + lane) * HW + hwb);
        float4 a0 = zrow[0], a1 = zrow[1], a2 = zrow[2], a3 = zrow[3];
        float* zr = ztf + (w * 64 + lane) * 17;
        zr[0] = a0.x; zr[1] = a0.y; zr[2] = a0.z; zr[3] = a0.w;
        zr[4] = a1.x; zr[5] = a1.y; zr[6] = a1.z; zr[7] = a1.w;
        zr[8] = a2.x; zr[9] = a2.y; zr[10] = a2.z; zr[11] = a2.w;
        zr[12] = a3.x; zr[13] = a3.y; zr[14] = a3.z; zr[15] = a3.w;
    }
    __syncthreads();

    if (t < 64)   // exact np-order ||z||^2 per pixel (fix path)
        szz_sh[t] = np_pairwise64_sq(
            [&](int i) { return ztf[((t >> 4) * 64 + i) * 17 + (t & 15)]; });

    // A fragments (hi/lo), wave-local rows of ztf
    bf16x8 Ah0, Ah1, Al0, Al1;
#pragma unroll
    for (int j = 0; j < 8; ++j) {
        float v0 = ztf[(w * 64 + q * 8 + j) * 17 + n];
        float v1 = ztf[(w * 64 + 32 + q * 8 + j) * 17 + n];
        __bf16 h0 = (__bf16)v0, h1 = (__bf16)v1;
        Ah0[j] = h0; Al0[j] = (__bf16)__fsub_rn(v0, (float)h0);
        Ah1[j] = h1; Al1[j] = (__bf16)__fsub_rn(v1, (float)h1);
    }

    float b0d[4], b1d[4]; int b0k[4];
#pragma unroll
    for (int e = 0; e < 4; ++e) { b0d[e] = 3.0e38f; b1d[e] = 3.0e38f; b0k[e] = 0; }

    // K-loop: 16 chunks x (stage 16KB to LDS, then 4 tiles x 6 MFMA)
    const float4* ebp4 = (const float4*)(ws + WS_EBP);
    for (int ch = 0; ch < 16; ++ch) {
        __syncthreads();                                 // prev chunk reads done
        {   // contiguous b128 copy: thread t -> float4 slots t, t+256, t+512, t+768
            const float4* src = ebp4 + (size_t)ch * 1024;
            float4* dst = (float4*)ldsB;
#pragma unroll
            for (int r = 0; r < 4; ++r) dst[t + r * 256] = src[t + r * 256];
        }
        __syncthreads();                                 // chunk staged
#pragma unroll
        for (int tt = 0; tt < 4; ++tt) {
            const char* base = ldsB + tt * 4096 + lane * 16;
            bf16x8 Bh0 = *(const bf16x8*)(base);
            bf16x8 Bl0 = *(const bf16x8*)(base + 1024);
            bf16x8 Bh1 = *(const bf16x8*)(base + 2048);
            bf16x8 Bl1 = *(const bf16x8*)(base + 3072);
            const int kk = ch * 64 + tt * 16 + n;
            const float se1v = se1[kk];
            f32x4 acc = {0.f, 0.f, 0.f, 0.f};
            acc = __builtin_amdgcn_mfma_f32_16x16x32_bf16(Ah0, Bh0, acc, 0, 0, 0);
            acc = __builtin_amdgcn_mfma_f32_16x16x32_bf16(Ah1, Bh1, acc, 0, 0, 0);
            acc = __builtin_amdgcn_mfma_f32_16x16x32_bf16(Ah0, Bl0, acc, 0, 0, 0);
            acc = __builtin_amdgcn_mfma_f32_16x16x32_bf16(Ah1, Bl1, acc, 0, 0, 0);
            acc = __builtin_amdgcn_mfma_f32_16x16x32_bf16(Al0, Bh0, acc, 0, 0, 0);
            acc = __builtin_amdgcn_mfma_f32_16x16x32_bf16(Al1, Bh1, acc, 0, 0, 0);
#pragma unroll
            for (int e = 0; e < 4; ++e) {
                float d = __builtin_fmaf(-2.0f, acc[e], se1v);  // 1+se-2dot > 0
                bool take = d < b0d[e];
                b1d[e] = __builtin_amdgcn_fmed3f(d, b0d[e], b1d[e]); // new 2nd-best
                b0k[e] = take ? kk : b0k[e];
                b0d[e] = fminf(b0d[e], d);
            }
        }
    }

    // merge top-2 across the 16 col-lanes of each quad group
#pragma unroll
    for (int m = 1; m < 16; m <<= 1) {
#pragma unroll
        for (int e = 0; e < 4; ++e) {
            float od = __shfl_xor(b0d[e], m, 16);
            int   ok = __shfl_xor(b0k[e], m, 16);
            float o1 = __shfl_xor(b1d[e], m, 16);
            b1d[e] = fminf(fminf(b1d[e], o1), fmaxf(b0d[e], od));
            bool take = (od < b0d[e]) || (od == b0d[e] && ok < b0k[e]);
            b0d[e] = take ? od : b0d[e];
            b0k[e] = take ? ok : b0k[e];
        }
    }
#pragma unroll
    for (int e = 0; e < 4; ++e) {
        if (n == e) {                                   // one writer per row q*4+e
            int local = w * 16 + q * 4 + e;
            s_kfinal[local] = b0k[e];
            if (__fsub_rn(b1d[e], b0d[e]) <= WINDOW) {
                int pos = atomicAdd(&s_cnt, 1);
                s_flag[pos] = local;
            }
        }
    }
    __syncthreads();

    // in-block exact fix (bit-exact reference numerics), one wave per flagged pixel
    const int cnt = s_cnt;
    for (int i = w; i < cnt; i += 4) {
        const int l = s_flag[i];
        float zv[64];
#pragma unroll
        for (int c = 0; c < 64; ++c)
            zv[c] = ztf[((l >> 4) * 64 + c) * 17 + (l & 15)];   // broadcast reads
        const float szz = szz_sh[l];
        unsigned long long best = ~0ULL;
        for (int it = 0; it < 16; ++it) {
            const int k = it * 64 + lane;
            const float* ek = emb + (size_t)k * CCH;
            float dot = 0.f;
#pragma unroll
            for (int c = 0; c < 64; ++c) dot = __builtin_fmaf(zv[c], ek[c], dot);
            float d = __fsub_rn(__fadd_rn(szz, sex[k]), __fadd_rn(dot, dot));
            unsigned long long cand =
                ((unsigned long long)__float_as_uint(d) << 32) | (unsigned)k;
            best = cand < best ? cand : best;
        }
#pragma unroll
        for (int m = 1; m < 64; m <<= 1) {
            unsigned long long o = __shfl_xor(best, m, 64);
            best = o < best ? o : best;
        }
        if (lane == 0) s_kfinal[l] = (int)(unsigned)best;
    }
    __syncthreads();

    // epilogue: gather + STE q-write + idx + losses (z from LDS, no re-read)
    float lsum = 0.f;
    {
        const int p = t & 63, cs = t >> 6;
        const int k = s_kfinal[p];
#pragma unroll
        for (int j = 0; j < 16; ++j) {
            const int c = cs * 16 + j;
            float e    = emb[(size_t)k * CCH + c];
            float zc   = ztf[((p >> 4) * 64 + c) * 17 + (p & 15)];
            float diff = __fsub_rn(e, zc);
            out[(size_t)(b * CCH + c) * HW + hw0 + p] = __fadd_rn(zc, diff);
            lsum = __builtin_fmaf(diff, diff, lsum);
        }
    }
    if (t < 64) out[IDX_OFF + pix0 + t] = (float)s_kfinal[t];
#pragma unroll
    for (int off = 32; off > 0; off >>= 1) lsum += __shfl_down(lsum, off, 64);
    if (lane == 0) s_red[w] = lsum;
    __syncthreads();
    if (t == 0) {
        float v = (s_red[0] + s_red[1] + s_red[2] + s_red[3]) * (1.0f / (float)Q_ELEMS);
        atomicAdd(out + LOSS0_OFF, v);
        atomicAdd(out + LOSS1_OFF, v);
    }
}

extern "C" void kernel_launch(void* const* d_in, const int* in_sizes, int n_in,
                              void* d_out, int out_size, void* d_ws, size_t ws_size,
                              hipStream_t stream) {
    const float* z   = (const float*)d_in[0];
    const float* emb = (const float*)d_in[1];
    float* out = (float*)d_out;
    char* ws = (char*)d_ws;

    prep_kernel<<<dim3(68),   dim3(256), 0, stream>>>(emb, ws, out);
    vq_all     <<<dim3(1024), dim3(256), 0, stream>>>(z, emb, ws, out);
}